// Round 1
// baseline (40200.281 us; speedup 1.0000x reference)
//
#include <hip/hip_runtime.h>
#include <hip/hip_cooperative_groups.h>
#include <cmath>

namespace cg = cooperative_groups;

#define IN_DIM 1024
#define HD 256
#define G4H 1024
#define BB 64
#define TT 512
#define NCLS 8

#define RING_SLOTS 4
#define RING_SLOT_STRIDE (BB * HD)                  /* 16384 floats */
#define RING_LAYER_STRIDE (RING_SLOTS * BB * HD)    /* 65536 floats */

__device__ __forceinline__ float sigmoidf_(float x) {
    return 1.0f / (1.0f + __expf(-x));
}

/* ---------------- Kernel 1: xg0 = x @ Wih0^T + b0, stored (B*T, 4H) ----------------
 * A = x (B*T, 1024) contiguous rows; B = Wih0 (1024, 1024); C = xg0 (B*T, 1024). */
#define BM 64
#define BN 64
#define BK 16

__global__ __launch_bounds__(256) void xg0_gemm(const float* __restrict__ x,
                                                const float* __restrict__ Wih0,
                                                const float* __restrict__ b0,
                                                float* __restrict__ xg0) {
    __shared__ float As[BK][BM];
    __shared__ float Bs[BK][BN];
    const int m0 = blockIdx.y * BM;
    const int n0 = blockIdx.x * BN;
    const int tid = threadIdx.x;
    const int tx = tid & 15;   // n micro
    const int ty = tid >> 4;   // m micro
    float acc[4][4] = {};
    for (int k0 = 0; k0 < IN_DIM; k0 += BK) {
        {
            const int r = tid >> 2;
            const int c = (tid & 3) << 2;
            const float4 v = *(const float4*)&x[(size_t)(m0 + r) * IN_DIM + k0 + c];
            As[c + 0][r] = v.x; As[c + 1][r] = v.y; As[c + 2][r] = v.z; As[c + 3][r] = v.w;
            const float4 w = *(const float4*)&Wih0[(size_t)(n0 + r) * IN_DIM + k0 + c];
            Bs[c + 0][r] = w.x; Bs[c + 1][r] = w.y; Bs[c + 2][r] = w.z; Bs[c + 3][r] = w.w;
        }
        __syncthreads();
#pragma unroll
        for (int k = 0; k < BK; ++k) {
            const float4 av = *(const float4*)&As[k][ty * 4];
            const float4 bv = *(const float4*)&Bs[k][tx * 4];
            acc[0][0] = fmaf(av.x, bv.x, acc[0][0]); acc[0][1] = fmaf(av.x, bv.y, acc[0][1]);
            acc[0][2] = fmaf(av.x, bv.z, acc[0][2]); acc[0][3] = fmaf(av.x, bv.w, acc[0][3]);
            acc[1][0] = fmaf(av.y, bv.x, acc[1][0]); acc[1][1] = fmaf(av.y, bv.y, acc[1][1]);
            acc[1][2] = fmaf(av.y, bv.z, acc[1][2]); acc[1][3] = fmaf(av.y, bv.w, acc[1][3]);
            acc[2][0] = fmaf(av.z, bv.x, acc[2][0]); acc[2][1] = fmaf(av.z, bv.y, acc[2][1]);
            acc[2][2] = fmaf(av.z, bv.z, acc[2][2]); acc[2][3] = fmaf(av.z, bv.w, acc[2][3]);
            acc[3][0] = fmaf(av.w, bv.x, acc[3][0]); acc[3][1] = fmaf(av.w, bv.y, acc[3][1]);
            acc[3][2] = fmaf(av.w, bv.z, acc[3][2]); acc[3][3] = fmaf(av.w, bv.w, acc[3][3]);
        }
        __syncthreads();
    }
    const float4 bias4 = *(const float4*)&b0[n0 + tx * 4];
#pragma unroll
    for (int i = 0; i < 4; ++i) {
        float4 v;
        v.x = acc[i][0] + bias4.x; v.y = acc[i][1] + bias4.y;
        v.z = acc[i][2] + bias4.z; v.w = acc[i][3] + bias4.w;
        *(float4*)&xg0[(size_t)(m0 + ty * 4 + i) * G4H + n0 + tx * 4] = v;
    }
}

/* ---------------- Kernel 2: wavefront-pipelined 3-layer LSTM recurrence ----------------
 * 192 blocks = 3 layer groups x 64 blocks. Block covers 16 b x 16 j; thread owns one
 * (b,j) and its 4 gate dots. c state in registers; h via 4-deep ring in ws. */
__global__ __launch_bounds__(256) void lstm_wave(
    const float* __restrict__ xg0,
    const float* __restrict__ Whh0,
    const float* __restrict__ Wih1, const float* __restrict__ Whh1, const float* __restrict__ b1,
    const float* __restrict__ Wih2, const float* __restrict__ Whh2, const float* __restrict__ b2,
    float* __restrict__ hring)
{
    cg::grid_group grid = cg::this_grid();
    const int blk = blockIdx.x;
    const int layer = blk >> 6;         // 0..2
    const int lb = blk & 63;
    const int bTile = lb >> 4;          // 0..3
    const int jTile = lb & 15;          // 0..15
    const int tid = threadIdx.x;
    const int b_local = tid >> 4;       // 0..15
    const int j_local = tid & 15;       // 0..15
    const int b = bTile * 16 + b_local;
    const int j = jTile * 16 + j_local;

    // zero all rings (ws is poisoned)
    for (int i = blk * 256 + tid; i < 3 * RING_LAYER_STRIDE; i += 192 * 256)
        hring[i] = 0.0f;

    float* myring = hring + layer * RING_LAYER_STRIDE;
    const float* inring = hring + (layer - 1) * RING_LAYER_STRIDE; // layer>=1 only

    const float* Wih = (layer == 1) ? Wih1 : Wih2;
    const float* Whh = (layer == 0) ? Whh0 : ((layer == 1) ? Whh1 : Whh2);
    const float* bias = (layer == 1) ? b1 : b2;

    const float* wh0 = Whh + (size_t)(0 * HD + j) * HD;
    const float* wh1 = Whh + (size_t)(1 * HD + j) * HD;
    const float* wh2 = Whh + (size_t)(2 * HD + j) * HD;
    const float* wh3 = Whh + (size_t)(3 * HD + j) * HD;
    const float* wi0 = Wih + (size_t)(0 * HD + j) * HD;
    const float* wi1 = Wih + (size_t)(1 * HD + j) * HD;
    const float* wi2 = Wih + (size_t)(2 * HD + j) * HD;
    const float* wi3 = Wih + (size_t)(3 * HD + j) * HD;
    float bs0 = 0.f, bs1 = 0.f, bs2 = 0.f, bs3 = 0.f;
    if (layer > 0) {
        bs0 = bias[0 * HD + j]; bs1 = bias[1 * HD + j];
        bs2 = bias[2 * HD + j]; bs3 = bias[3 * HD + j];
    }

    __shared__ float hin[16][HD];
    __shared__ float hpv[16][HD];

    float c = 0.0f;

    grid.sync();

    for (int tick = 0; tick < TT + 2; ++tick) {
        const int t = tick - layer;
        if (t >= 0 && t < TT) {
            // stage h_prev tile (16 x 256)
            {
                const float* src = myring + (size_t)((t + RING_SLOTS - 1) & 3) * RING_SLOT_STRIDE
                                 + (size_t)(bTile * 16) * HD;
                const int r = tid >> 4;
                const int q = (tid & 15) << 4;
                float4* dst4 = (float4*)&hpv[r][q];
                const float4* src4 = (const float4*)&src[r * HD + q];
                dst4[0] = src4[0]; dst4[1] = src4[1]; dst4[2] = src4[2]; dst4[3] = src4[3];
            }
            if (layer > 0) {  // stage input h tile from previous layer
                const float* src = inring + (size_t)(t & 3) * RING_SLOT_STRIDE
                                 + (size_t)(bTile * 16) * HD;
                const int r = tid >> 4;
                const int q = (tid & 15) << 4;
                float4* dst4 = (float4*)&hin[r][q];
                const float4* src4 = (const float4*)&src[r * HD + q];
                dst4[0] = src4[0]; dst4[1] = src4[1]; dst4[2] = src4[2]; dst4[3] = src4[3];
            }
            __syncthreads();

            float a0, a1, a2, a3;
            if (layer == 0) {
                const float* xgp = xg0 + ((size_t)b * TT + t) * G4H + j;
                a0 = xgp[0 * HD]; a1 = xgp[1 * HD]; a2 = xgp[2 * HD]; a3 = xgp[3 * HD];
            } else {
                a0 = bs0; a1 = bs1; a2 = bs2; a3 = bs3;
#pragma unroll 4
                for (int k = 0; k < HD; k += 4) {
                    const float4 xv = *(const float4*)&hin[b_local][k];
                    const float4 w0 = *(const float4*)&wi0[k];
                    const float4 w1 = *(const float4*)&wi1[k];
                    const float4 w2 = *(const float4*)&wi2[k];
                    const float4 w3 = *(const float4*)&wi3[k];
                    a0 = fmaf(xv.x, w0.x, a0); a0 = fmaf(xv.y, w0.y, a0);
                    a0 = fmaf(xv.z, w0.z, a0); a0 = fmaf(xv.w, w0.w, a0);
                    a1 = fmaf(xv.x, w1.x, a1); a1 = fmaf(xv.y, w1.y, a1);
                    a1 = fmaf(xv.z, w1.z, a1); a1 = fmaf(xv.w, w1.w, a1);
                    a2 = fmaf(xv.x, w2.x, a2); a2 = fmaf(xv.y, w2.y, a2);
                    a2 = fmaf(xv.z, w2.z, a2); a2 = fmaf(xv.w, w2.w, a2);
                    a3 = fmaf(xv.x, w3.x, a3); a3 = fmaf(xv.y, w3.y, a3);
                    a3 = fmaf(xv.z, w3.z, a3); a3 = fmaf(xv.w, w3.w, a3);
                }
            }
#pragma unroll 4
            for (int k = 0; k < HD; k += 4) {
                const float4 hv = *(const float4*)&hpv[b_local][k];
                const float4 w0 = *(const float4*)&wh0[k];
                const float4 w1 = *(const float4*)&wh1[k];
                const float4 w2 = *(const float4*)&wh2[k];
                const float4 w3 = *(const float4*)&wh3[k];
                a0 = fmaf(hv.x, w0.x, a0); a0 = fmaf(hv.y, w0.y, a0);
                a0 = fmaf(hv.z, w0.z, a0); a0 = fmaf(hv.w, w0.w, a0);
                a1 = fmaf(hv.x, w1.x, a1); a1 = fmaf(hv.y, w1.y, a1);
                a1 = fmaf(hv.z, w1.z, a1); a1 = fmaf(hv.w, w1.w, a1);
                a2 = fmaf(hv.x, w2.x, a2); a2 = fmaf(hv.y, w2.y, a2);
                a2 = fmaf(hv.z, w2.z, a2); a2 = fmaf(hv.w, w2.w, a2);
                a3 = fmaf(hv.x, w3.x, a3); a3 = fmaf(hv.y, w3.y, a3);
                a3 = fmaf(hv.z, w3.z, a3); a3 = fmaf(hv.w, w3.w, a3);
            }
            const float ig = sigmoidf_(a0);
            const float fg = sigmoidf_(a1);
            const float gg = tanhf(a2);
            const float og = sigmoidf_(a3);
            c = fg * c + ig * gg;
            const float h = og * tanhf(c);
            myring[(size_t)(t & 3) * RING_SLOT_STRIDE + (size_t)b * HD + j] = h;
        }
        grid.sync();
    }
}

/* ---------------- Kernel 3: FC head on h2[T-1] ---------------- */
__global__ __launch_bounds__(256) void classifier_k(
    const float* __restrict__ hring,
    const float* __restrict__ W1, const float* __restrict__ bfc1,
    const float* __restrict__ W2, const float* __restrict__ bfc2,
    float* __restrict__ out)
{
    __shared__ float z[BB * 128];
    const float* h2 = hring + 2 * RING_LAYER_STRIDE + (size_t)((TT - 1) & 3) * RING_SLOT_STRIDE;
    const int tid = threadIdx.x;
    for (int idx = tid; idx < BB * 128; idx += 256) {
        const int bb = idx >> 7;
        const int n = idx & 127;
        float acc = bfc1[n];
        const float* hr = h2 + (size_t)bb * HD;
        const float* wr = W1 + (size_t)n * HD;
        for (int k = 0; k < HD; k += 4) {
            const float4 hv = *(const float4*)&hr[k];
            const float4 wv = *(const float4*)&wr[k];
            acc = fmaf(hv.x, wv.x, acc); acc = fmaf(hv.y, wv.y, acc);
            acc = fmaf(hv.z, wv.z, acc); acc = fmaf(hv.w, wv.w, acc);
        }
        z[idx] = fmaxf(acc, 0.0f);
    }
    __syncthreads();
    for (int idx = tid; idx < BB * NCLS; idx += 256) {
        const int bb = idx >> 3;
        const int n = idx & 7;
        float acc = bfc2[n];
        const float* zr = &z[bb * 128];
        const float* wr = W2 + (size_t)n * 128;
        for (int k = 0; k < 128; k += 4) {
            const float4 zv = *(const float4*)&zr[k];
            const float4 wv = *(const float4*)&wr[k];
            acc = fmaf(zv.x, wv.x, acc); acc = fmaf(zv.y, wv.y, acc);
            acc = fmaf(zv.z, wv.z, acc); acc = fmaf(zv.w, wv.w, acc);
        }
        out[idx] = acc;
    }
}

extern "C" void kernel_launch(void* const* d_in, const int* in_sizes, int n_in,
                              void* d_out, int out_size, void* d_ws, size_t ws_size,
                              hipStream_t stream) {
    const float* x    = (const float*)d_in[0];
    const float* Wih0 = (const float*)d_in[1];
    const float* Whh0 = (const float*)d_in[2];
    const float* b0   = (const float*)d_in[3];
    const float* Wih1 = (const float*)d_in[4];
    const float* Whh1 = (const float*)d_in[5];
    const float* b1   = (const float*)d_in[6];
    const float* Wih2 = (const float*)d_in[7];
    const float* Whh2 = (const float*)d_in[8];
    const float* b2   = (const float*)d_in[9];
    const float* W1   = (const float*)d_in[10];
    const float* bfc1 = (const float*)d_in[11];
    const float* W2   = (const float*)d_in[12];
    const float* bfc2 = (const float*)d_in[13];

    float* xg0   = (float*)d_ws;                       // B*T*4H fp32 = 134.2 MB
    float* hring = xg0 + (size_t)BB * TT * G4H;        // 3*4*B*H fp32 = 786 KB

    xg0_gemm<<<dim3(G4H / BN, (BB * TT) / BM), 256, 0, stream>>>(x, Wih0, b0, xg0);

    const float* xg0c = xg0;
    float* hr = hring;
    void* args[] = {
        (void*)&xg0c, (void*)&Whh0,
        (void*)&Wih1, (void*)&Whh1, (void*)&b1,
        (void*)&Wih2, (void*)&Whh2, (void*)&b2,
        (void*)&hr
    };
    hipLaunchCooperativeKernel((void*)lstm_wave, dim3(192), dim3(256), args, 0, stream);

    classifier_k<<<1, 256, 0, stream>>>(hring, W1, bfc1, W2, bfc2, (float*)d_out);
}

// Round 2
// 14148.128 us; speedup vs baseline: 2.8414x; 2.8414x over previous
//
#include <hip/hip_runtime.h>
#include <hip/hip_cooperative_groups.h>
#include <cmath>

namespace cg = cooperative_groups;

#define IN_DIM 1024
#define HD 256
#define G4H 1024
#define BB 64
#define TT 512
#define NCLS 8

/* h rings: 3 layers x 4 slots x [k(=j)][b] transposed, 16384 floats per slot */
#define SLOT_STRIDE (HD * BB)          /* 16384 floats */
#define LAYER_STRIDE (4 * SLOT_STRIDE) /* 65536 floats */

__device__ __forceinline__ float sigmoidf_(float x) {
    return 1.0f / (1.0f + __expf(-x));
}

__device__ __forceinline__ void wait_ge(int* f, int n) {
    while (__hip_atomic_load(f, __ATOMIC_RELAXED, __HIP_MEMORY_SCOPE_AGENT) < n) {
        __builtin_amdgcn_s_sleep(1);
    }
}

/* ---------------- Kernel 1: xg0 = x @ Wih0^T + b0, stored (B*T, 4H) ----------------
 * 128x128 tile, BK=16, 8x8 micro-tile per thread. M=B*T=32768, N=1024, K=1024. */
#define GBM 128
#define GBN 128
#define GBK 16

__global__ __launch_bounds__(256) void xg0_gemm(const float* __restrict__ x,
                                                const float* __restrict__ Wih0,
                                                const float* __restrict__ b0,
                                                float* __restrict__ xg0) {
    __shared__ float As[GBK][GBM];
    __shared__ float Bs[GBK][GBN];
    const int m0 = blockIdx.y * GBM;
    const int n0 = blockIdx.x * GBN;
    const int tid = threadIdx.x;
    const int tx = tid & 15;   // n micro (8 cols)
    const int ty = tid >> 4;   // m micro (8 rows)
    const int lr = tid >> 1;          // 0..127 staging row
    const int lk = (tid & 1) * 8;     // 0 or 8
    float acc[8][8] = {};
    for (int k0 = 0; k0 < IN_DIM; k0 += GBK) {
        const float4 a0 = *(const float4*)&x[(size_t)(m0 + lr) * IN_DIM + k0 + lk];
        const float4 a1 = *(const float4*)&x[(size_t)(m0 + lr) * IN_DIM + k0 + lk + 4];
        const float4 w0 = *(const float4*)&Wih0[(size_t)(n0 + lr) * IN_DIM + k0 + lk];
        const float4 w1 = *(const float4*)&Wih0[(size_t)(n0 + lr) * IN_DIM + k0 + lk + 4];
        __syncthreads();
        As[lk + 0][lr] = a0.x; As[lk + 1][lr] = a0.y; As[lk + 2][lr] = a0.z; As[lk + 3][lr] = a0.w;
        As[lk + 4][lr] = a1.x; As[lk + 5][lr] = a1.y; As[lk + 6][lr] = a1.z; As[lk + 7][lr] = a1.w;
        Bs[lk + 0][lr] = w0.x; Bs[lk + 1][lr] = w0.y; Bs[lk + 2][lr] = w0.z; Bs[lk + 3][lr] = w0.w;
        Bs[lk + 4][lr] = w1.x; Bs[lk + 5][lr] = w1.y; Bs[lk + 6][lr] = w1.z; Bs[lk + 7][lr] = w1.w;
        __syncthreads();
#pragma unroll
        for (int k = 0; k < GBK; ++k) {
            const float4 av0 = *(const float4*)&As[k][ty * 8];
            const float4 av1 = *(const float4*)&As[k][ty * 8 + 4];
            const float4 bv0 = *(const float4*)&Bs[k][tx * 8];
            const float4 bv1 = *(const float4*)&Bs[k][tx * 8 + 4];
            const float am[8] = {av0.x, av0.y, av0.z, av0.w, av1.x, av1.y, av1.z, av1.w};
            const float bn[8] = {bv0.x, bv0.y, bv0.z, bv0.w, bv1.x, bv1.y, bv1.z, bv1.w};
#pragma unroll
            for (int i = 0; i < 8; ++i)
#pragma unroll
                for (int jj = 0; jj < 8; ++jj)
                    acc[i][jj] = fmaf(am[i], bn[jj], acc[i][jj]);
        }
    }
    const float4 bias0 = *(const float4*)&b0[n0 + tx * 8];
    const float4 bias1 = *(const float4*)&b0[n0 + tx * 8 + 4];
#pragma unroll
    for (int i = 0; i < 8; ++i) {
        const int m = m0 + ty * 8 + i;
        float4 v0, v1;
        v0.x = acc[i][0] + bias0.x; v0.y = acc[i][1] + bias0.y;
        v0.z = acc[i][2] + bias0.z; v0.w = acc[i][3] + bias0.w;
        v1.x = acc[i][4] + bias1.x; v1.y = acc[i][5] + bias1.y;
        v1.z = acc[i][6] + bias1.z; v1.w = acc[i][7] + bias1.w;
        *(float4*)&xg0[(size_t)m * G4H + n0 + tx * 8] = v0;
        *(float4*)&xg0[(size_t)m * G4H + n0 + tx * 8 + 4] = v1;
    }
}

/* ---------------- Kernel 2: 3-stage flag-synced LSTM recurrence ----------------
 * 192 blocks = 3 layers x 64 blocks. Block owns 4 j-columns (all 4 gates, LDS-resident
 * weights, 32 KB) and all 64 batches. Thread = (j_local = tid>>6, b = tid&63); each wave
 * is one j (wave-uniform LDS weight reads = broadcast). h rings transposed [k][b] so
 * per-k reads/writes are lane-coalesced. Producer/consumer sync via device-scope flags. */
__global__ __launch_bounds__(256) void lstm_cells(
    const float* __restrict__ xg0,
    const float* __restrict__ Whh0,
    const float* __restrict__ Wih1, const float* __restrict__ Whh1, const float* __restrict__ b1,
    const float* __restrict__ Wih2, const float* __restrict__ Whh2, const float* __restrict__ b2,
    float* __restrict__ hring, int* __restrict__ flags)
{
    cg::grid_group grid = cg::this_grid();
    const int blk = blockIdx.x;
    const int layer = blk >> 6;        // 0..2
    const int lb = blk & 63;
    const int jbase = lb * 4;
    const int tid = threadIdx.x;
    const int jl = tid >> 6;           // 0..3 (wave-uniform)
    const int b = tid & 63;
    const int j = jbase + jl;

    __shared__ float wlds[8192];       // [mat(2)][gate(4)][jl(4)][k(256)] = 32 KB

    const float* Wih = (layer == 1) ? Wih1 : Wih2;
    const float* Whh = (layer == 0) ? Whh0 : ((layer == 1) ? Whh1 : Whh2);
    const float* bias = (layer == 1) ? b1 : b2;

    // stage weights into LDS (once)
    const int nrows = (layer == 0) ? 16 : 32;
    for (int idx = tid; idx < nrows * 256; idx += 256) {
        const int row = idx >> 8;
        const int k = idx & 255;
        int mat, g, j2;
        if (layer == 0) { mat = 1; g = row >> 2; j2 = row & 3; }
        else            { mat = row >> 4; g = (row >> 2) & 3; j2 = row & 3; }
        const float* src = mat ? Whh : Wih;
        wlds[((mat * 4 + g) * 4 + j2) * 256 + k] = src[(size_t)(g * 256 + jbase + j2) * 256 + k];
    }

    // zero rings + flags (ws is poisoned)
    for (int i = blk * 256 + tid; i < 3 * LAYER_STRIDE; i += 192 * 256) hring[i] = 0.0f;
    for (int i = blk * 256 + tid; i < 3 * TT; i += 192 * 256) flags[i] = 0;

    float bs0 = 0.f, bs1 = 0.f, bs2 = 0.f, bs3 = 0.f;
    if (layer > 0) {
        bs0 = bias[0 * HD + j]; bs1 = bias[1 * HD + j];
        bs2 = bias[2 * HD + j]; bs3 = bias[3 * HD + j];
    }

    float* myring = hring + layer * LAYER_STRIDE;
    const float* inring = hring + (layer - 1) * LAYER_STRIDE;
    int* mydone  = flags + layer * TT;
    int* indone  = flags + (layer - 1) * TT;
    int* nxtdone = flags + (layer + 1) * TT;

    const float* w_ih0 = &wlds[((0 * 4 + 0) * 4 + jl) * 256];
    const float* w_ih1 = &wlds[((0 * 4 + 1) * 4 + jl) * 256];
    const float* w_ih2 = &wlds[((0 * 4 + 2) * 4 + jl) * 256];
    const float* w_ih3 = &wlds[((0 * 4 + 3) * 4 + jl) * 256];
    const float* w_hh0 = &wlds[((1 * 4 + 0) * 4 + jl) * 256];
    const float* w_hh1 = &wlds[((1 * 4 + 1) * 4 + jl) * 256];
    const float* w_hh2 = &wlds[((1 * 4 + 2) * 4 + jl) * 256];
    const float* w_hh3 = &wlds[((1 * 4 + 3) * 4 + jl) * 256];

    float c = 0.0f;

    grid.sync();   // flags/rings zeroed + weights staged, visible everywhere

    for (int t = 0; t < TT; ++t) {
        if (tid == 0) {
            if (layer > 0) wait_ge(&indone[t], 64);         // input h_{l-1}[t]
            if (t >= 1)    wait_ge(&mydone[t - 1], 64);     // own h_l[t-1]
            if (layer < 2 && t >= 4) wait_ge(&nxtdone[t - 4], 64);  // slot-reuse guard
            __threadfence();                                 // acquire: invalidate stale caches
        }
        __syncthreads();

        float x0, x1, x2, x3;
        if (layer == 0) {
            const float* xg = xg0 + ((size_t)b * TT + t) * G4H + j;
            x0 = xg[0 * HD]; x1 = xg[1 * HD]; x2 = xg[2 * HD]; x3 = xg[3 * HD];
        } else {
            const float* hin = inring + (size_t)(t & 3) * SLOT_STRIDE;  // [k][b]
            float4 p0 = {0,0,0,0}, p1 = {0,0,0,0}, p2 = {0,0,0,0}, p3 = {0,0,0,0};
#pragma unroll 2
            for (int k = 0; k < HD; k += 4) {
                const float hv0 = hin[(k + 0) * BB + b];
                const float hv1 = hin[(k + 1) * BB + b];
                const float hv2 = hin[(k + 2) * BB + b];
                const float hv3 = hin[(k + 3) * BB + b];
                const float4 wv0 = *(const float4*)&w_ih0[k];
                const float4 wv1 = *(const float4*)&w_ih1[k];
                const float4 wv2 = *(const float4*)&w_ih2[k];
                const float4 wv3 = *(const float4*)&w_ih3[k];
                p0.x = fmaf(wv0.x, hv0, p0.x); p0.y = fmaf(wv0.y, hv1, p0.y);
                p0.z = fmaf(wv0.z, hv2, p0.z); p0.w = fmaf(wv0.w, hv3, p0.w);
                p1.x = fmaf(wv1.x, hv0, p1.x); p1.y = fmaf(wv1.y, hv1, p1.y);
                p1.z = fmaf(wv1.z, hv2, p1.z); p1.w = fmaf(wv1.w, hv3, p1.w);
                p2.x = fmaf(wv2.x, hv0, p2.x); p2.y = fmaf(wv2.y, hv1, p2.y);
                p2.z = fmaf(wv2.z, hv2, p2.z); p2.w = fmaf(wv2.w, hv3, p2.w);
                p3.x = fmaf(wv3.x, hv0, p3.x); p3.y = fmaf(wv3.y, hv1, p3.y);
                p3.z = fmaf(wv3.z, hv2, p3.z); p3.w = fmaf(wv3.w, hv3, p3.w);
            }
            x0 = bs0 + (p0.x + p0.y) + (p0.z + p0.w);
            x1 = bs1 + (p1.x + p1.y) + (p1.z + p1.w);
            x2 = bs2 + (p2.x + p2.y) + (p2.z + p2.w);
            x3 = bs3 + (p3.x + p3.y) + (p3.z + p3.w);
        }

        {   // hh part: h_l[t-1] from own ring slot (t+3)&3 (zeroed for t=0)
            const float* hpv = myring + (size_t)((t + 3) & 3) * SLOT_STRIDE;
            float4 q0 = {0,0,0,0}, q1 = {0,0,0,0}, q2 = {0,0,0,0}, q3 = {0,0,0,0};
#pragma unroll 2
            for (int k = 0; k < HD; k += 4) {
                const float hv0 = hpv[(k + 0) * BB + b];
                const float hv1 = hpv[(k + 1) * BB + b];
                const float hv2 = hpv[(k + 2) * BB + b];
                const float hv3 = hpv[(k + 3) * BB + b];
                const float4 wv0 = *(const float4*)&w_hh0[k];
                const float4 wv1 = *(const float4*)&w_hh1[k];
                const float4 wv2 = *(const float4*)&w_hh2[k];
                const float4 wv3 = *(const float4*)&w_hh3[k];
                q0.x = fmaf(wv0.x, hv0, q0.x); q0.y = fmaf(wv0.y, hv1, q0.y);
                q0.z = fmaf(wv0.z, hv2, q0.z); q0.w = fmaf(wv0.w, hv3, q0.w);
                q1.x = fmaf(wv1.x, hv0, q1.x); q1.y = fmaf(wv1.y, hv1, q1.y);
                q1.z = fmaf(wv1.z, hv2, q1.z); q1.w = fmaf(wv1.w, hv3, q1.w);
                q2.x = fmaf(wv2.x, hv0, q2.x); q2.y = fmaf(wv2.y, hv1, q2.y);
                q2.z = fmaf(wv2.z, hv2, q2.z); q2.w = fmaf(wv2.w, hv3, q2.w);
                q3.x = fmaf(wv3.x, hv0, q3.x); q3.y = fmaf(wv3.y, hv1, q3.y);
                q3.z = fmaf(wv3.z, hv2, q3.z); q3.w = fmaf(wv3.w, hv3, q3.w);
            }
            const float a0 = x0 + (q0.x + q0.y) + (q0.z + q0.w);
            const float a1 = x1 + (q1.x + q1.y) + (q1.z + q1.w);
            const float a2 = x2 + (q2.x + q2.y) + (q2.z + q2.w);
            const float a3 = x3 + (q3.x + q3.y) + (q3.z + q3.w);

            const float ig = sigmoidf_(a0);
            const float fg = sigmoidf_(a1);
            const float gg = tanhf(a2);
            const float og = sigmoidf_(a3);
            c = fg * c + ig * gg;
            const float h = og * tanhf(c);
            myring[(size_t)(t & 3) * SLOT_STRIDE + (size_t)j * BB + b] = h;  // [j][b] coalesced
        }

        __syncthreads();   // drains vmcnt(0): all block h-stores are in L2
        if (tid == 0) {
            __threadfence();                                  // release: write back to agent scope
            atomicAdd(&mydone[t], 1);                         // device-scope by default
        }
    }
}

/* ---------------- Kernel 3: FC head on h2[T-1] (transposed [k][b] layout) ---------------- */
__global__ __launch_bounds__(256) void classifier_k(
    const float* __restrict__ hring,
    const float* __restrict__ W1, const float* __restrict__ bfc1,
    const float* __restrict__ W2, const float* __restrict__ bfc2,
    float* __restrict__ out)
{
    __shared__ float z[BB * 128];
    const float* h2T = hring + 2 * LAYER_STRIDE + (size_t)((TT - 1) & 3) * SLOT_STRIDE; // [k][b]
    const int tid = threadIdx.x;
    for (int idx = tid; idx < BB * 128; idx += 256) {
        const int bb = idx >> 7;
        const int n = idx & 127;
        float acc = bfc1[n];
        const float* wr = W1 + (size_t)n * HD;
        for (int k = 0; k < HD; ++k)
            acc = fmaf(h2T[k * BB + bb], wr[k], acc);
        z[bb * 128 + n] = fmaxf(acc, 0.0f);
    }
    __syncthreads();
    for (int idx = tid; idx < BB * NCLS; idx += 256) {
        const int bb = idx >> 3;
        const int n = idx & 7;
        float acc = bfc2[n];
        const float* zr = &z[bb * 128];
        const float* wr = W2 + (size_t)n * 128;
        for (int k = 0; k < 128; k += 4) {
            const float4 zv = *(const float4*)&zr[k];
            const float4 wv = *(const float4*)&wr[k];
            acc = fmaf(zv.x, wv.x, acc); acc = fmaf(zv.y, wv.y, acc);
            acc = fmaf(zv.z, wv.z, acc); acc = fmaf(zv.w, wv.w, acc);
        }
        out[idx] = acc;
    }
}

extern "C" void kernel_launch(void* const* d_in, const int* in_sizes, int n_in,
                              void* d_out, int out_size, void* d_ws, size_t ws_size,
                              hipStream_t stream) {
    const float* x    = (const float*)d_in[0];
    const float* Wih0 = (const float*)d_in[1];
    const float* Whh0 = (const float*)d_in[2];
    const float* b0   = (const float*)d_in[3];
    const float* Wih1 = (const float*)d_in[4];
    const float* Whh1 = (const float*)d_in[5];
    const float* b1   = (const float*)d_in[6];
    const float* Wih2 = (const float*)d_in[7];
    const float* Whh2 = (const float*)d_in[8];
    const float* b2   = (const float*)d_in[9];
    const float* W1   = (const float*)d_in[10];
    const float* bfc1 = (const float*)d_in[11];
    const float* W2   = (const float*)d_in[12];
    const float* bfc2 = (const float*)d_in[13];

    float* xg0   = (float*)d_ws;                       // B*T*4H fp32 = 134.2 MB
    float* hring = xg0 + (size_t)BB * TT * G4H;        // 3*4*16384 fp32 = 786 KB
    int*   flags = (int*)(hring + 3 * LAYER_STRIDE);   // 3*512 ints = 6 KB

    xg0_gemm<<<dim3(G4H / GBN, (BB * TT) / GBM), 256, 0, stream>>>(x, Wih0, b0, xg0);

    const float* xg0c = xg0;
    float* hr = hring;
    int* fl = flags;
    void* args[] = {
        (void*)&xg0c, (void*)&Whh0,
        (void*)&Wih1, (void*)&Whh1, (void*)&b1,
        (void*)&Wih2, (void*)&Whh2, (void*)&b2,
        (void*)&hr, (void*)&fl
    };
    hipLaunchCooperativeKernel((void*)lstm_cells, dim3(192), dim3(256), args, 0, stream);

    classifier_k<<<1, 256, 0, stream>>>(hring, W1, bfc1, W2, bfc2, (float*)d_out);
}

// Round 3
// 11791.677 us; speedup vs baseline: 3.4092x; 1.1998x over previous
//
#include <hip/hip_runtime.h>
#include <hip/hip_cooperative_groups.h>
#include <cmath>

namespace cg = cooperative_groups;

#define IN_DIM 1024
#define HD 256
#define G4H 1024
#define BB 64
#define TT 512
#define NCLS 8

/* h rings: 3 layers x 4 slots x [k(=j)][b], 16384 floats per slot */
#define SLOT_STRIDE (HD * BB)          /* 16384 floats */
#define LAYER_STRIDE (4 * SLOT_STRIDE) /* 65536 floats */

__device__ __forceinline__ float sigmoidf_(float x) {
    return 1.0f / (1.0f + __expf(-x));
}
__device__ __forceinline__ float tanhf_(float x) {
    return 2.0f / (1.0f + __expf(-2.0f * x)) - 1.0f;
}
__device__ __forceinline__ float ld_agent(const float* p) {
    return __hip_atomic_load(p, __ATOMIC_RELAXED, __HIP_MEMORY_SCOPE_AGENT);
}
__device__ __forceinline__ void st_agent(float* p, float v) {
    __hip_atomic_store(p, v, __ATOMIC_RELAXED, __HIP_MEMORY_SCOPE_AGENT);
}

/* ---------------- Kernel 1: xg0 = x @ Wih0^T + b0, stored (B*T, 4H) ---------------- */
#define GBM 128
#define GBN 128
#define GBK 16

__global__ __launch_bounds__(256) void xg0_gemm(const float* __restrict__ x,
                                                const float* __restrict__ Wih0,
                                                const float* __restrict__ b0,
                                                float* __restrict__ xg0) {
    __shared__ float As[GBK][GBM];
    __shared__ float Bs[GBK][GBN];
    const int m0 = blockIdx.y * GBM;
    const int n0 = blockIdx.x * GBN;
    const int tid = threadIdx.x;
    const int tx = tid & 15;
    const int ty = tid >> 4;
    const int lr = tid >> 1;
    const int lk = (tid & 1) * 8;
    float acc[8][8] = {};
    for (int k0 = 0; k0 < IN_DIM; k0 += GBK) {
        const float4 a0 = *(const float4*)&x[(size_t)(m0 + lr) * IN_DIM + k0 + lk];
        const float4 a1 = *(const float4*)&x[(size_t)(m0 + lr) * IN_DIM + k0 + lk + 4];
        const float4 w0 = *(const float4*)&Wih0[(size_t)(n0 + lr) * IN_DIM + k0 + lk];
        const float4 w1 = *(const float4*)&Wih0[(size_t)(n0 + lr) * IN_DIM + k0 + lk + 4];
        __syncthreads();
        As[lk + 0][lr] = a0.x; As[lk + 1][lr] = a0.y; As[lk + 2][lr] = a0.z; As[lk + 3][lr] = a0.w;
        As[lk + 4][lr] = a1.x; As[lk + 5][lr] = a1.y; As[lk + 6][lr] = a1.z; As[lk + 7][lr] = a1.w;
        Bs[lk + 0][lr] = w0.x; Bs[lk + 1][lr] = w0.y; Bs[lk + 2][lr] = w0.z; Bs[lk + 3][lr] = w0.w;
        Bs[lk + 4][lr] = w1.x; Bs[lk + 5][lr] = w1.y; Bs[lk + 6][lr] = w1.z; Bs[lk + 7][lr] = w1.w;
        __syncthreads();
#pragma unroll
        for (int k = 0; k < GBK; ++k) {
            const float4 av0 = *(const float4*)&As[k][ty * 8];
            const float4 av1 = *(const float4*)&As[k][ty * 8 + 4];
            const float4 bv0 = *(const float4*)&Bs[k][tx * 8];
            const float4 bv1 = *(const float4*)&Bs[k][tx * 8 + 4];
            const float am[8] = {av0.x, av0.y, av0.z, av0.w, av1.x, av1.y, av1.z, av1.w};
            const float bn[8] = {bv0.x, bv0.y, bv0.z, bv0.w, bv1.x, bv1.y, bv1.z, bv1.w};
#pragma unroll
            for (int i = 0; i < 8; ++i)
#pragma unroll
                for (int jj = 0; jj < 8; ++jj)
                    acc[i][jj] = fmaf(am[i], bn[jj], acc[i][jj]);
        }
    }
    const float4 bias0 = *(const float4*)&b0[n0 + tx * 8];
    const float4 bias1 = *(const float4*)&b0[n0 + tx * 8 + 4];
#pragma unroll
    for (int i = 0; i < 8; ++i) {
        const int m = m0 + ty * 8 + i;
        float4 v0, v1;
        v0.x = acc[i][0] + bias0.x; v0.y = acc[i][1] + bias0.y;
        v0.z = acc[i][2] + bias0.z; v0.w = acc[i][3] + bias0.w;
        v1.x = acc[i][4] + bias1.x; v1.y = acc[i][5] + bias1.y;
        v1.z = acc[i][6] + bias1.z; v1.w = acc[i][7] + bias1.w;
        *(float4*)&xg0[(size_t)m * G4H + n0 + tx * 8] = v0;
        *(float4*)&xg0[(size_t)m * G4H + n0 + tx * 8 + 4] = v1;
    }
}

/* ---------------- Kernel 2: 3-stage flag-synced LSTM, K-split waves, SGPR weights ----------------
 * 192 blocks = 3 layers x 64 blocks. Block owns 4 j (16 gate-rows) x all 64 b.
 * Wave w computes PARTIALS over k-chunk [64w,64w+64) for all 16 rows (lane = b,
 * weights wave-uniform -> scalar loads, normal caching). h rings accessed only via
 * agent-scope (sc1) loads/stores -> coherent through LLC, NO fences, caches stay warm.
 * Per-block done flags (no atomic RMW contention), 64-lane parallel poll. */
__global__ __launch_bounds__(256) void lstm_cells(
    const float* __restrict__ xg0,
    const float* __restrict__ Whh0,
    const float* __restrict__ Wih1, const float* __restrict__ Whh1, const float* __restrict__ b1,
    const float* __restrict__ Wih2, const float* __restrict__ Whh2, const float* __restrict__ b2,
    float* __restrict__ hring, int* __restrict__ flags)
{
    cg::grid_group grid = cg::this_grid();
    const int blk = blockIdx.x;
    const int layer = blk >> 6;        // 0..2
    const int lb = blk & 63;
    const int jbase = lb * 4;
    const int tid = threadIdx.x;
    const int w = tid >> 6;            // wave index 0..3 == cell j-local
    const int b = tid & 63;            // lane == batch
    const int kbase = w * 64;

    __shared__ float red[16 * 4 * 64]; // [row][wave][b] = 16 KB

    const float* Wih = (layer == 1) ? Wih1 : Wih2;
    const float* Whh = (layer == 0) ? Whh0 : ((layer == 1) ? Whh1 : Whh2);
    const float* bias = (layer == 1) ? b1 : b2;

    // zero rings + flags (ws is poisoned); plain stores, pushed out by grid.sync's release
    for (int i = blk * 256 + tid; i < 3 * LAYER_STRIDE; i += 192 * 256) hring[i] = 0.0f;
    for (int i = blk * 256 + tid; i < 3 * TT * 64; i += 192 * 256) flags[i] = 0;

    float bs0 = 0.f, bs1 = 0.f, bs2 = 0.f, bs3 = 0.f;
    if (layer > 0) {
        bs0 = bias[0 * HD + jbase + w]; bs1 = bias[1 * HD + jbase + w];
        bs2 = bias[2 * HD + jbase + w]; bs3 = bias[3 * HD + jbase + w];
    }

    float* myring = hring + layer * LAYER_STRIDE;
    const float* inring = hring + (layer - 1) * LAYER_STRIDE;

    float c = 0.0f;

    grid.sync();   // rings/flags zeroed and visible device-wide

    for (int t = 0; t < TT; ++t) {
        /* ---- wait for dependencies: wave 0 polls 64 per-block flags in parallel ---- */
        if (tid < 64) {
            const int* f_in  = &flags[((layer - 1) * TT + t) * 64 + tid];
            const int* f_own = &flags[(layer * TT + (t - 1)) * 64 + tid];
            const int* f_nxt = &flags[((layer + 1) * TT + (t - 4)) * 64 + tid];
            const bool need_in  = (layer > 0);
            const bool need_own = (t >= 1);
            const bool need_nxt = (layer < 2) && (t >= 4);
            for (;;) {
                int ok = 1;
                if (need_in)  ok &= __hip_atomic_load(f_in,  __ATOMIC_RELAXED, __HIP_MEMORY_SCOPE_AGENT);
                if (need_own) ok &= __hip_atomic_load(f_own, __ATOMIC_RELAXED, __HIP_MEMORY_SCOPE_AGENT);
                if (need_nxt) ok &= __hip_atomic_load(f_nxt, __ATOMIC_RELAXED, __HIP_MEMORY_SCOPE_AGENT);
                if (__all(ok)) break;
                __builtin_amdgcn_s_sleep(1);
            }
        }
        __syncthreads();
        __atomic_signal_fence(__ATOMIC_SEQ_CST);

        /* ---- layer-0: xg gate values (plain cached loads, issued early) ---- */
        float xv0, xv1, xv2, xv3;
        if (layer == 0) {
            const float* xg = xg0 + ((size_t)b * TT + t) * G4H + jbase + w;
            xv0 = xg[0 * HD]; xv1 = xg[1 * HD]; xv2 = xg[2 * HD]; xv3 = xg[3 * HD];
        }

        float acc[16];
#pragma unroll
        for (int r = 0; r < 16; ++r) acc[r] = 0.0f;

        /* ---- partials: hh over own h[t-1], k-chunk of this wave ---- */
        {
            const float* hpv = myring + (size_t)((t + 3) & 3) * SLOT_STRIDE;
            for (int kk = 0; kk < 64; kk += 16) {
                const int kb = kbase + kk;
                float hv[16];
#pragma unroll
                for (int u = 0; u < 16; ++u) hv[u] = ld_agent(&hpv[(kb + u) * BB + b]);
#pragma unroll
                for (int jl = 0; jl < 4; ++jl)
#pragma unroll
                    for (int g = 0; g < 4; ++g) {
                        const float* wr = Whh + (size_t)(g * HD + jbase + jl) * HD + kb;
                        float a = acc[jl * 4 + g];
#pragma unroll
                        for (int u = 0; u < 16; ++u) a = fmaf(wr[u], hv[u], a);
                        acc[jl * 4 + g] = a;
                    }
            }
        }
        /* ---- partials: ih over h_{l-1}[t] (layers 1,2) ---- */
        if (layer > 0) {
            const float* hin = inring + (size_t)(t & 3) * SLOT_STRIDE;
            for (int kk = 0; kk < 64; kk += 16) {
                const int kb = kbase + kk;
                float hv[16];
#pragma unroll
                for (int u = 0; u < 16; ++u) hv[u] = ld_agent(&hin[(kb + u) * BB + b]);
#pragma unroll
                for (int jl = 0; jl < 4; ++jl)
#pragma unroll
                    for (int g = 0; g < 4; ++g) {
                        const float* wr = Wih + (size_t)(g * HD + jbase + jl) * HD + kb;
                        float a = acc[jl * 4 + g];
#pragma unroll
                        for (int u = 0; u < 16; ++u) a = fmaf(wr[u], hv[u], a);
                        acc[jl * 4 + g] = a;
                    }
            }
        }

        /* ---- cross-wave reduction via LDS: red[row][wave][b] ---- */
#pragma unroll
        for (int r = 0; r < 16; ++r) red[(r * 4 + w) * 64 + b] = acc[r];
        __syncthreads();

        /* ---- cell update: thread = (j = w, b) ---- */
        {
            float a0, a1, a2, a3;
            if (layer == 0) { a0 = xv0; a1 = xv1; a2 = xv2; a3 = xv3; }
            else            { a0 = bs0; a1 = bs1; a2 = bs2; a3 = bs3; }
#pragma unroll
            for (int ww = 0; ww < 4; ++ww) {
                a0 += red[((w * 4 + 0) * 4 + ww) * 64 + b];
                a1 += red[((w * 4 + 1) * 4 + ww) * 64 + b];
                a2 += red[((w * 4 + 2) * 4 + ww) * 64 + b];
                a3 += red[((w * 4 + 3) * 4 + ww) * 64 + b];
            }
            const float ig = sigmoidf_(a0);
            const float fg = sigmoidf_(a1);
            const float gg = tanhf_(a2);
            const float og = sigmoidf_(a3);
            c = fg * c + ig * gg;
            const float h = og * tanhf_(c);
            st_agent(&myring[(size_t)(t & 3) * SLOT_STRIDE + (size_t)(jbase + w) * BB + b], h);
        }

        __syncthreads();   // compiler drains vmcnt(0) per wave before barrier -> h at LLC
        if (tid == 0) {
            __hip_atomic_store(&flags[(layer * TT + t) * 64 + lb], 1,
                               __ATOMIC_RELAXED, __HIP_MEMORY_SCOPE_AGENT);
        }
    }
}

/* ---------------- Kernel 3: FC head on h2[T-1] ([k][b] layout) ---------------- */
__global__ __launch_bounds__(256) void classifier_k(
    const float* __restrict__ hring,
    const float* __restrict__ W1, const float* __restrict__ bfc1,
    const float* __restrict__ W2, const float* __restrict__ bfc2,
    float* __restrict__ out)
{
    __shared__ float z[BB * 128];
    const float* h2T = hring + 2 * LAYER_STRIDE + (size_t)((TT - 1) & 3) * SLOT_STRIDE;
    const int tid = threadIdx.x;
    for (int idx = tid; idx < BB * 128; idx += 256) {
        const int bb = idx >> 7;
        const int n = idx & 127;
        float acc = bfc1[n];
        const float* wr = W1 + (size_t)n * HD;
        for (int k = 0; k < HD; ++k)
            acc = fmaf(h2T[k * BB + bb], wr[k], acc);
        z[bb * 128 + n] = fmaxf(acc, 0.0f);
    }
    __syncthreads();
    for (int idx = tid; idx < BB * NCLS; idx += 256) {
        const int bb = idx >> 3;
        const int n = idx & 7;
        float acc = bfc2[n];
        const float* zr = &z[bb * 128];
        const float* wr = W2 + (size_t)n * 128;
        for (int k = 0; k < 128; k += 4) {
            const float4 zv = *(const float4*)&zr[k];
            const float4 wv = *(const float4*)&wr[k];
            acc = fmaf(zv.x, wv.x, acc); acc = fmaf(zv.y, wv.y, acc);
            acc = fmaf(zv.z, wv.z, acc); acc = fmaf(zv.w, wv.w, acc);
        }
        out[idx] = acc;
    }
}

extern "C" void kernel_launch(void* const* d_in, const int* in_sizes, int n_in,
                              void* d_out, int out_size, void* d_ws, size_t ws_size,
                              hipStream_t stream) {
    const float* x    = (const float*)d_in[0];
    const float* Wih0 = (const float*)d_in[1];
    const float* Whh0 = (const float*)d_in[2];
    const float* b0   = (const float*)d_in[3];
    const float* Wih1 = (const float*)d_in[4];
    const float* Whh1 = (const float*)d_in[5];
    const float* b1   = (const float*)d_in[6];
    const float* Wih2 = (const float*)d_in[7];
    const float* Whh2 = (const float*)d_in[8];
    const float* b2   = (const float*)d_in[9];
    const float* W1   = (const float*)d_in[10];
    const float* bfc1 = (const float*)d_in[11];
    const float* W2   = (const float*)d_in[12];
    const float* bfc2 = (const float*)d_in[13];

    float* xg0   = (float*)d_ws;                       // B*T*4H fp32 = 134.2 MB
    float* hring = xg0 + (size_t)BB * TT * G4H;        // 786 KB
    int*   flags = (int*)(hring + 3 * LAYER_STRIDE);   // 3*512*64 ints = 393 KB

    xg0_gemm<<<dim3(G4H / GBN, (BB * TT) / GBM), 256, 0, stream>>>(x, Wih0, b0, xg0);

    const float* xg0c = xg0;
    float* hr = hring;
    int* fl = flags;
    void* args[] = {
        (void*)&xg0c, (void*)&Whh0,
        (void*)&Wih1, (void*)&Whh1, (void*)&b1,
        (void*)&Wih2, (void*)&Whh2, (void*)&b2,
        (void*)&hr, (void*)&fl
    };
    hipLaunchCooperativeKernel((void*)lstm_cells, dim3(192), dim3(256), args, 0, stream);

    classifier_k<<<1, 256, 0, stream>>>(hring, W1, bfc1, W2, bfc2, (float*)d_out);
}